// Round 2
// baseline (227.611 us; speedup 1.0000x reference)
//
#include <hip/hip_runtime.h>

typedef float f4 __attribute__((ext_vector_type(4)));

#define HH 128
#define WW 128
#define NPIX 16384
#define NC 32
#define NO 32
#define KS 9
#define TAPS 81
#define DIL 2
#define PAD 8
#define OG 8                  // output-channel groups (blockIdx.y)
#define OPG 4                 // outputs per thread
#define SMAX 27.6310211159f   // s <= SMAX  <=>  exp(-0.5 s) >= 1e-6 (skip bound 80*1e-6*|t| << 8.8e-4)

#define NT (NC * NPIX)        // 524288 transposed x/f elements
#define NW (NO * NC * TAPS)   // 82944 weight elements
#define NMASK 768             // 256 pixel-waves * 3 u32 words

// ---------------------------------------------------------------------------
// prep: transpose x,f -> (pix,c); W1,W2 -> [tap][o][c]; zero live-tap masks.
// Reads coalesced; scattered writes merge in L2 (total volume ~4.7 MB).
// ---------------------------------------------------------------------------
__global__ __launch_bounds__(256) void prep_kernel(
    const float* __restrict__ x, const float* __restrict__ f,
    const float* __restrict__ W1, const float* __restrict__ W2,
    float* __restrict__ xt, float* __restrict__ ft,
    float* __restrict__ W1t, float* __restrict__ W2t,
    unsigned* __restrict__ live)
{
    int tid = blockIdx.x * 256 + threadIdx.x;
    if (tid < NT) {
        int c = tid >> 14, pix = tid & (NPIX - 1);
        xt[pix * NC + c] = x[tid];
        ft[pix * NC + c] = f[tid];
    } else if (tid < NT + NW) {
        int t = tid - NT;
        int o = t / (NC * TAPS);
        int r = t - o * (NC * TAPS);
        int c = r / TAPS;
        int tap = r - c * TAPS;
        W1t[tap * (NO * NC) + o * NC + c] = W1[t];
        W2t[tap * (NO * NC) + o * NC + c] = W2[t];
    } else if (tid < NT + NW + NMASK) {
        live[tid - NT - NW] = 0u;
    }
}

// ---------------------------------------------------------------------------
// mask: per 64-pixel wave, vote each of 81 taps live if any lane has
// valid neighbor && ||f_q - f_p||^2 <= SMAX. One thread per (kernel-row, pix).
// ---------------------------------------------------------------------------
__global__ __launch_bounds__(256) void mask_kernel(
    const float* __restrict__ ft, unsigned* __restrict__ live)
{
    int tid = blockIdx.x * 256 + threadIdx.x;   // KS*NPIX threads
    int pix = tid & (NPIX - 1);
    int i = tid >> 14;                           // kernel row 0..8
    int h = pix >> 7, w = pix & (WW - 1);

    f4 fc[8];
    const f4* fp = (const f4*)(ft + pix * NC);
#pragma unroll
    for (int c4 = 0; c4 < 8; ++c4) fc[c4] = fp[c4];

    int qh = h + i * DIL - PAD;
    bool vh = (unsigned)qh < HH;
#pragma unroll
    for (int j = 0; j < KS; ++j) {
        int qw = w + j * DIL - PAD;
        bool valid = vh && ((unsigned)qw < WW);
        int q = qh * WW + qw;
        float s = 1e30f;
        if (valid) {
            s = 0.f;
            const f4* fq = (const f4*)(ft + q * NC);
#pragma unroll
            for (int c4 = 0; c4 < 8; ++c4) {
                f4 fn = fq[c4];
#pragma unroll
                for (int e = 0; e < 4; ++e) {
                    float d = fn[e] - fc[c4][e];
                    s = fmaf(d, d, s);
                }
            }
        }
        unsigned long long bal = __ballot(valid && (s <= SMAX));
        int tap = i * KS + j;
        if (bal != 0ull && (threadIdx.x & 63) == 0)
            atomicOr(&live[(pix >> 6) * 3 + (tap >> 5)], 1u << (tap & 31));
    }
}

// ---------------------------------------------------------------------------
// pac: one PAC layer over live taps only.
//   in, ft in (pix,c) layout; Wt in [tap][o][c]; per-wave scalar tap loop.
//   acc[o] += exp(-0.5||df||^2) * sum_c in[q,c] * W[o,c,tap]
// No LDS. Weights load via scalar pipe (uniform address after readfirstlane).
// TOUT: true -> write (pix,o) transposed (layer 1), false -> (o,pix) (layer 2).
// ---------------------------------------------------------------------------
template <bool TOUT>
__global__ __launch_bounds__(256) void pac_kernel(
    const float* __restrict__ in, const float* __restrict__ ft,
    const unsigned* __restrict__ live, const float* __restrict__ Wt,
    const float* __restrict__ bias, float* __restrict__ out)
{
    const int pix = blockIdx.x * 256 + threadIdx.x;
    const int og = blockIdx.y;
    const int h = pix >> 7, w = pix & (WW - 1);
    const int wv = pix >> 6;

    f4 fc[8];
    const f4* fp = (const f4*)(ft + pix * NC);
#pragma unroll
    for (int c4 = 0; c4 < 8; ++c4) fc[c4] = fp[c4];

    float acc[OPG] = {0.f, 0.f, 0.f, 0.f};

    for (int word = 0; word < 3; ++word) {
        unsigned m = (unsigned)__builtin_amdgcn_readfirstlane((int)live[wv * 3 + word]);
        while (m) {
            int b = __builtin_ctz(m);
            m &= m - 1;
            int tap = __builtin_amdgcn_readfirstlane(word * 32 + b);  // wave-uniform
            int i = tap / KS, j = tap - i * KS;
            int qh = h + i * DIL - PAD;
            int qw = w + j * DIL - PAD;
            bool valid = ((unsigned)qh < HH) & ((unsigned)qw < WW);
            int q = qh * WW + qw;

            f4 xin[8], fn[8];
#pragma unroll
            for (int c4 = 0; c4 < 8; ++c4) { xin[c4] = (f4)0.f; fn[c4] = (f4)0.f; }
            if (valid) {
                const f4* xq = (const f4*)(in + q * NC);
                const f4* fq = (const f4*)(ft + q * NC);
#pragma unroll
                for (int c4 = 0; c4 < 8; ++c4) { xin[c4] = xq[c4]; fn[c4] = fq[c4]; }
            }

            const float* wp = Wt + tap * (NO * NC) + og * (OPG * NC);  // uniform -> s_load
            float s = 0.f;
            float t0 = 0.f, t1 = 0.f, t2 = 0.f, t3 = 0.f;
#pragma unroll
            for (int c4 = 0; c4 < 8; ++c4) {
#pragma unroll
                for (int e = 0; e < 4; ++e) {
                    int c = c4 * 4 + e;
                    float d = fn[c4][e] - fc[c4][e];
                    s = fmaf(d, d, s);
                    float xv = xin[c4][e];
                    t0 = fmaf(xv, wp[0 * NC + c], t0);
                    t1 = fmaf(xv, wp[1 * NC + c], t1);
                    t2 = fmaf(xv, wp[2 * NC + c], t2);
                    t3 = fmaf(xv, wp[3 * NC + c], t3);
                }
            }
            float kv = __expf(-0.5f * s);
            acc[0] = fmaf(kv, t0, acc[0]);
            acc[1] = fmaf(kv, t1, acc[1]);
            acc[2] = fmaf(kv, t2, acc[2]);
            acc[3] = fmaf(kv, t3, acc[3]);
        }
    }

    if (TOUT) {
        f4 r;
#pragma unroll
        for (int o = 0; o < OPG; ++o) r[o] = acc[o] + bias[og * OPG + o];
        *(f4*)(out + pix * NC + og * OPG) = r;
    } else {
#pragma unroll
        for (int o = 0; o < OPG; ++o)
            out[(og * OPG + o) * NPIX + pix] = acc[o] + bias[og * OPG + o];
    }
}

// ---------------------------------------------------------------------------
// Fallback (round-1 proven path, needs only 2 MB ws) in case ws is small.
// ---------------------------------------------------------------------------
#define CHUNK 27
#define NCHUNK 3
#define KMIN 1e-6f
__global__ __launch_bounds__(256) void pac_layer_fuse(
    const float* __restrict__ in, const float* __restrict__ f,
    const float* __restrict__ Wt, const float* __restrict__ bias,
    float* __restrict__ out)
{
    __shared__ float wl[NC * CHUNK * 8];
    const int og = blockIdx.y;
    const int pix = blockIdx.x * 256 + threadIdx.x;
    const int h = pix >> 7, w = pix & (WW - 1);
    float acc[8];
#pragma unroll
    for (int i = 0; i < 8; ++i) acc[i] = 0.f;
    float fc[NC];
#pragma unroll
    for (int c = 0; c < NC; ++c) fc[c] = f[c * NPIX + pix];
    for (int ch = 0; ch < NCHUNK; ++ch) {
        __syncthreads();
        for (int idx = threadIdx.x; idx < NC * CHUNK * 8; idx += 256) {
            int t = idx % CHUNK;
            int c = (idx / CHUNK) % NC;
            int o = idx / (CHUNK * NC);
            wl[(c * CHUNK + t) * 8 + o] =
                Wt[(og * 8 + o) * (NC * TAPS) + c * TAPS + ch * CHUNK + t];
        }
        __syncthreads();
        for (int t = 0; t < CHUNK; ++t) {
            int tap = ch * CHUNK + t;
            int qh = h + (tap / KS) * DIL - PAD;
            int qw = w + (tap % KS) * DIL - PAD;
            bool valid = ((unsigned)qh < HH) & ((unsigned)qw < WW);
            int q = qh * WW + qw;
            float s = 0.f;
#pragma unroll
            for (int c = 0; c < NC; ++c) {
                float fn = valid ? f[c * NPIX + q] : 0.f;
                float d = fn - fc[c];
                s = fmaf(d, d, s);
            }
            float kv = __expf(-0.5f * s);
            if (__all((kv < KMIN) | (!valid))) continue;
            const float* wpp = &wl[t * 8];
#pragma unroll 8
            for (int c = 0; c < NC; ++c) {
                float v = valid ? in[c * NPIX + q] : 0.f;
                v *= kv;
#pragma unroll
                for (int o = 0; o < 8; ++o)
                    acc[o] = fmaf(v, wpp[c * CHUNK * 8 + o], acc[o]);
            }
        }
    }
#pragma unroll
    for (int o = 0; o < 8; ++o)
        out[(og * 8 + o) * NPIX + pix] = acc[o] + bias[og * 8 + o];
}

// ---------------------------------------------------------------------------
extern "C" void kernel_launch(void* const* d_in, const int* in_sizes, int n_in,
                              void* d_out, int out_size, void* d_ws, size_t ws_size,
                              hipStream_t stream)
{
    (void)in_sizes; (void)n_in; (void)out_size;
    const float* x  = (const float*)d_in[0];
    const float* f  = (const float*)d_in[1];
    const float* W1 = (const float*)d_in[2];
    const float* b1 = (const float*)d_in[3];
    const float* W2 = (const float*)d_in[4];
    const float* b2 = (const float*)d_in[5];
    float* out = (float*)d_out;

    float* ws = (float*)d_ws;
    float* ht = ws;                                 // NT floats (layer-1 out, (pix,c))
    unsigned* live = (unsigned*)(ws + NT);          // NMASK u32
    float* W1t = ws + NT + NMASK;                   // NW
    float* W2t = W1t + NW;                          // NW
    float* xt  = W2t + NW;                          // NT
    float* ftb = xt + NT;                           // NT
    const size_t need = (size_t)(3 * NT + NMASK + 2 * NW) * sizeof(float);  // ~6.96 MB

    if (ws_size >= need) {
        prep_kernel<<<(NT + NW + NMASK + 255) / 256, 256, 0, stream>>>(
            x, f, W1, W2, xt, ftb, W1t, W2t, live);
        mask_kernel<<<KS * NPIX / 256, 256, 0, stream>>>(ftb, live);
        dim3 grid(NPIX / 256, OG);
        pac_kernel<true ><<<grid, 256, 0, stream>>>(xt, ftb, live, W1t, b1, ht);
        pac_kernel<false><<<grid, 256, 0, stream>>>(ht, ftb, live, W2t, b2, out);
    } else {
        float* hbuf = ws;   // 2 MB
        pac_layer_fuse<<<dim3(64, 4), 256, 0, stream>>>(x, f, W1, b1, hbuf);
        pac_layer_fuse<<<dim3(64, 4), 256, 0, stream>>>(hbuf, f, W2, b2, out);
    }
}

// Round 3
// 154.711 us; speedup vs baseline: 1.4712x; 1.4712x over previous
//
#include <hip/hip_runtime.h>

#define HH 128
#define WW 128
#define NPIX 16384
#define NC 32
#define NO 32
#define KS 9
#define TAPS 81
#define DIL 2
#define PAD 8
#define SMAX 27.6310211159f   // s <= SMAX <=> exp(-0.5 s) >= 1e-6; dropped-tap bound ~1.4e-5 << 8.8e-4
#define NW (NO * NC * TAPS)   // 82944
#define NWAVE 256             // 64-pixel waves
#define OG 8                  // output groups
#define OPG 4                 // outputs per thread

// ---------------------------------------------------------------------------
// K1: guidance kv per (tap,pix) for live taps + per-(wave,taprow) 9-bit live
// masks (no atomics: each wave owns its word) + weight transpose to
// [tap][og][o][c] so pac's weight reads are wave-uniform -> scalar s_loads.
// f stays in original (c,pix) layout: all loads 256 B coalesced per wave.
// ---------------------------------------------------------------------------
__global__ __launch_bounds__(256) void prep_k_kernel(
    const float* __restrict__ f,
    const float* __restrict__ W1, const float* __restrict__ W2,
    float* __restrict__ kbuf, unsigned* __restrict__ live9,
    float* __restrict__ W1t, float* __restrict__ W2t)
{
    const int i = blockIdx.y;
    if (i == KS) {                       // 64 blocks: transpose both weights
        for (int t = blockIdx.x * 256 + threadIdx.x; t < NW; t += 64 * 256) {
            int o = t / (NC * TAPS);
            int r = t - o * (NC * TAPS);
            int c = r / TAPS;
            int tap = r - c * TAPS;
            int d = ((tap * OG + (o >> 2)) * OPG + (o & 3)) * NC + c;
            W1t[d] = W1[t];
            W2t[d] = W2[t];
        }
        return;
    }
    const int pix = blockIdx.x * 256 + threadIdx.x;
    const int h = pix >> 7, w = pix & (WW - 1);
    const int wv = pix >> 6;

    float fc[NC];
#pragma unroll
    for (int c = 0; c < NC; ++c) fc[c] = f[c * NPIX + pix];

    const int qh = h + i * DIL - PAD;
    const bool vh = (unsigned)qh < HH;
    unsigned wmask = 0;
#pragma unroll
    for (int j = 0; j < KS; ++j) {
        int qw = w + j * DIL - PAD;
        bool valid = vh & ((unsigned)qw < WW);
        int q = valid ? (qh * WW + qw) : pix;   // safe addr for masked lanes
        float s0 = 0.f, s1 = 0.f, s2 = 0.f, s3 = 0.f;
#pragma unroll
        for (int c4 = 0; c4 < 8; ++c4) {
            float d0 = f[(4 * c4 + 0) * NPIX + q] - fc[4 * c4 + 0];
            float d1 = f[(4 * c4 + 1) * NPIX + q] - fc[4 * c4 + 1];
            float d2 = f[(4 * c4 + 2) * NPIX + q] - fc[4 * c4 + 2];
            float d3 = f[(4 * c4 + 3) * NPIX + q] - fc[4 * c4 + 3];
            s0 = fmaf(d0, d0, s0); s1 = fmaf(d1, d1, s1);
            s2 = fmaf(d2, d2, s2); s3 = fmaf(d3, d3, s3);
        }
        float s = (s0 + s1) + (s2 + s3);
        s = valid ? s : 1e30f;                  // invalid lanes -> kv = 0
        unsigned long long bal = __ballot(s <= SMAX);
        if (bal) {                               // wave-uniform branch
            wmask |= 1u << j;
            kbuf[(i * KS + j) * NPIX + pix] = __expf(-0.5f * s);
        }
    }
    if ((threadIdx.x & 63) == 0) live9[wv * KS + i] = wmask;
}

// ---------------------------------------------------------------------------
// pac: one layer. in/out in (c,pix) layout. Per-wave scalar iterator over
// live taps; software-pipelined (ping-pong xA/xB): tap B's loads issue while
// tap A's 128 FMAs retire. Weights via wave-uniform s_load (no LDS).
// kv==0 at invalid lanes makes OOB contributions vanish without cndmask.
// ---------------------------------------------------------------------------
__global__ __launch_bounds__(256) void pac_kernel(
    const float* __restrict__ in, const float* __restrict__ kbuf,
    const unsigned* __restrict__ live9, const float* __restrict__ Wt,
    const float* __restrict__ bias, float* __restrict__ out)
{
    const int pix = blockIdx.x * 256 + threadIdx.x;
    const int og = blockIdx.y;
    const int h = pix >> 7, w = pix & (WW - 1);
    const int wv = pix >> 6;

    int i = 0;
    unsigned m = (unsigned)__builtin_amdgcn_readfirstlane((int)live9[wv * KS + 0]);
    auto next = [&]() -> int {                 // wave-uniform tap iterator
        while (m == 0) {
            if (++i >= KS) return -1;
            m = (unsigned)__builtin_amdgcn_readfirstlane((int)live9[wv * KS + i]);
        }
        int j = __builtin_ctz(m);
        m &= m - 1;
        return (i << 4) | j;
    };

    float acc0 = 0.f, acc1 = 0.f, acc2 = 0.f, acc3 = 0.f;
    float xA[NC], xB[NC];
    float kvA, kvB;
    const float* wpA; const float* wpB;

#define LOAD(tp, X, KV, WP) do {                                           \
        int ii = (tp) >> 4, jj = (tp) & 15;                                \
        int qh_ = h + ii * DIL - PAD;                                      \
        int qw_ = w + jj * DIL - PAD;                                      \
        bool valid_ = ((unsigned)qh_ < HH) & ((unsigned)qw_ < WW);         \
        int q_ = valid_ ? (qh_ * WW + qw_) : pix;                          \
        KV = kbuf[(ii * KS + jj) * NPIX + pix];                            \
        WP = Wt + ((ii * KS + jj) * OG + og) * (OPG * NC);                 \
        _Pragma("unroll")                                                  \
        for (int c = 0; c < NC; ++c) X[c] = in[c * NPIX + q_];             \
    } while (0)

#define CONSUME(X, KV, WP) do {                                            \
        float t0 = 0.f, t1 = 0.f, t2 = 0.f, t3 = 0.f;                      \
        _Pragma("unroll")                                                  \
        for (int c = 0; c < NC; ++c) {                                     \
            float xv = X[c];                                               \
            t0 = fmaf(xv, WP[0 * NC + c], t0);                             \
            t1 = fmaf(xv, WP[1 * NC + c], t1);                             \
            t2 = fmaf(xv, WP[2 * NC + c], t2);                             \
            t3 = fmaf(xv, WP[3 * NC + c], t3);                             \
        }                                                                  \
        acc0 = fmaf(KV, t0, acc0); acc1 = fmaf(KV, t1, acc1);              \
        acc2 = fmaf(KV, t2, acc2); acc3 = fmaf(KV, t3, acc3);              \
    } while (0)

    int tapA = next();
    if (tapA >= 0) {
        LOAD(tapA, xA, kvA, wpA);
        for (;;) {
            int tapB = next();
            if (tapB < 0) { CONSUME(xA, kvA, wpA); break; }
            LOAD(tapB, xB, kvB, wpB);
            CONSUME(xA, kvA, wpA);
            tapA = next();
            if (tapA < 0) { CONSUME(xB, kvB, wpB); break; }
            LOAD(tapA, xA, kvA, wpA);
            CONSUME(xB, kvB, wpB);
        }
    }
#undef LOAD
#undef CONSUME

    out[(og * OPG + 0) * NPIX + pix] = acc0 + bias[og * OPG + 0];
    out[(og * OPG + 1) * NPIX + pix] = acc1 + bias[og * OPG + 1];
    out[(og * OPG + 2) * NPIX + pix] = acc2 + bias[og * OPG + 2];
    out[(og * OPG + 3) * NPIX + pix] = acc3 + bias[og * OPG + 3];
}

// ---------------------------------------------------------------------------
// Fallback (round-1 proven path, 2 MB ws) in case ws is small.
// ---------------------------------------------------------------------------
#define CHUNK 27
#define NCHUNK 3
#define KMIN 1e-6f
__global__ __launch_bounds__(256) void pac_layer_fuse(
    const float* __restrict__ in, const float* __restrict__ f,
    const float* __restrict__ Wt, const float* __restrict__ bias,
    float* __restrict__ out)
{
    __shared__ float wl[NC * CHUNK * 8];
    const int og = blockIdx.y;
    const int pix = blockIdx.x * 256 + threadIdx.x;
    const int h = pix >> 7, w = pix & (WW - 1);
    float acc[8];
#pragma unroll
    for (int i = 0; i < 8; ++i) acc[i] = 0.f;
    float fc[NC];
#pragma unroll
    for (int c = 0; c < NC; ++c) fc[c] = f[c * NPIX + pix];
    for (int ch = 0; ch < NCHUNK; ++ch) {
        __syncthreads();
        for (int idx = threadIdx.x; idx < NC * CHUNK * 8; idx += 256) {
            int t = idx % CHUNK;
            int c = (idx / CHUNK) % NC;
            int o = idx / (CHUNK * NC);
            wl[(c * CHUNK + t) * 8 + o] =
                Wt[(og * 8 + o) * (NC * TAPS) + c * TAPS + ch * CHUNK + t];
        }
        __syncthreads();
        for (int t = 0; t < CHUNK; ++t) {
            int tap = ch * CHUNK + t;
            int qh = h + (tap / KS) * DIL - PAD;
            int qw = w + (tap % KS) * DIL - PAD;
            bool valid = ((unsigned)qh < HH) & ((unsigned)qw < WW);
            int q = qh * WW + qw;
            float s = 0.f;
#pragma unroll
            for (int c = 0; c < NC; ++c) {
                float fn = valid ? f[c * NPIX + q] : 0.f;
                float d = fn - fc[c];
                s = fmaf(d, d, s);
            }
            float kv = __expf(-0.5f * s);
            if (__all((kv < KMIN) | (!valid))) continue;
            const float* wpp = &wl[t * 8];
#pragma unroll 8
            for (int c = 0; c < NC; ++c) {
                float v = valid ? in[c * NPIX + q] : 0.f;
                v *= kv;
#pragma unroll
                for (int o = 0; o < 8; ++o)
                    acc[o] = fmaf(v, wpp[c * CHUNK * 8 + o], acc[o]);
            }
        }
    }
#pragma unroll
    for (int o = 0; o < 8; ++o)
        out[(og * 8 + o) * NPIX + pix] = acc[o] + bias[og * 8 + o];
}

// ---------------------------------------------------------------------------
extern "C" void kernel_launch(void* const* d_in, const int* in_sizes, int n_in,
                              void* d_out, int out_size, void* d_ws, size_t ws_size,
                              hipStream_t stream)
{
    (void)in_sizes; (void)n_in; (void)out_size;
    const float* x  = (const float*)d_in[0];
    const float* f  = (const float*)d_in[1];
    const float* W1 = (const float*)d_in[2];
    const float* b1 = (const float*)d_in[3];
    const float* W2 = (const float*)d_in[4];
    const float* b2 = (const float*)d_in[5];
    float* out = (float*)d_out;

    float* ws = (float*)d_ws;
    float* kbuf = ws;                                    // TAPS*NPIX
    unsigned* live9 = (unsigned*)(ws + TAPS * NPIX);     // NWAVE*KS
    float* W1t = ws + TAPS * NPIX + NWAVE * KS;          // NW
    float* W2t = W1t + NW;                               // NW
    float* ht  = W2t + NW;                               // NO*NPIX
    const size_t need =
        (size_t)(TAPS * NPIX + NWAVE * KS + 2 * NW + NO * NPIX) * sizeof(float);

    if (ws_size >= need) {
        prep_k_kernel<<<dim3(64, KS + 1), 256, 0, stream>>>(
            f, W1, W2, kbuf, live9, W1t, W2t);
        pac_kernel<<<dim3(64, OG), 256, 0, stream>>>(x,  kbuf, live9, W1t, b1, ht);
        pac_kernel<<<dim3(64, OG), 256, 0, stream>>>(ht, kbuf, live9, W2t, b2, out);
    } else {
        float* hbuf = ws;
        pac_layer_fuse<<<dim3(64, 4), 256, 0, stream>>>(x, f, W1, b1, hbuf);
        pac_layer_fuse<<<dim3(64, 4), 256, 0, stream>>>(hbuf, f, W2, b2, out);
    }
}